// Round 4
// baseline (562.223 us; speedup 1.0000x reference)
//
#include <hip/hip_runtime.h>
#include <hip/hip_bf16.h>
#include <stdint.h>

#define B_     2048
#define WIN_   11
#define K_     4096
#define VOCAB_ 30522
#define NOUT_  18
#define TOPK_  64
#define NPAIR_ (B_ * WIN_)         /* 22528 */
#define PI_F   3.14159274101257324f

#define NCH_    15                 /* chunks per k-slice */
#define CHUNK_  2048               /* entries; 16 KB; 1 global_load_lds per thread */
#define KPB_    16                 /* k per persistent block */
#define NBLK_   (K_ / KPB_)        /* 256 blocks = 1 per CU */
#define GTOT_   (NCH_ * KPB_)      /* 240 chunk-phases per block */
#define PFTH_   1024
#define PCON_BYTES_ (NPAIR_ * 4)                    /* 90112 */
#define SMEM_BYTES_ (PCON_BYTES_ + 4 * CHUNK_ * 8)  /* 155648 <= 160 KiB */

// ---------------------------------------------------------------------------
// Kernel A: per-batch window prep -> cos/sin per (b,w)
// ---------------------------------------------------------------------------
__global__ void prep_kernel(const int* __restrict__ ids, float2* __restrict__ ocs) {
    int b = blockIdx.x * blockDim.x + threadIdx.x;
    if (b >= B_) return;
    const int* row = ids + b * WIN_;
    int poss[WIN_];
    int cnt = 0;
#pragma unroll
    for (int w = 0; w < WIN_; ++w) { cnt += (row[w] != 0); poss[w] = cnt; }
    float fsl = (float)((cnt > 0) ? cnt : WIN_);
#pragma unroll
    for (int w = 0; w < WIN_; ++w) {
        float pos = __fdiv_rn(__fmul_rn(PI_F, (float)poss[w]), fsl);
        float2 o;
        o.x = cosf(pos);
        o.y = sinf(pos);
        ocs[b * WIN_ + w] = o;
    }
}

// ---------------------------------------------------------------------------
// Kernel A2: stable deterministic bucket-by-chunk of the 22528 (b,w) pairs.
// smeta[pos] = {id, pairidx, cos, sin}; chunkstart[0..NCH_].
// ---------------------------------------------------------------------------
__global__ __launch_bounds__(512) void bucket_kernel(const int* __restrict__ ids,
                                                     const float2* __restrict__ ocs,
                                                     float4* __restrict__ smeta,
                                                     int* __restrict__ chunkstart) {
    __shared__ int lcnt[512 * NCH_];
    __shared__ int segtot[NCH_][8];
    __shared__ int tot[NCH_];
    __shared__ int bbase[NCH_ + 1];
    const int t = threadIdx.x;

#pragma unroll
    for (int c = 0; c < NCH_; ++c) lcnt[t * NCH_ + c] = 0;
    __syncthreads();

    for (int p = t; p < NPAIR_; p += 512) {
        int id = ids[p];
        if (id != 0) lcnt[t * NCH_ + (id / CHUNK_)] += 1;
    }
    __syncthreads();

    if (t < NCH_ * 8) {
        int bkt = t >> 3, seg = t & 7;
        int run = 0;
        for (int i = 0; i < 64; ++i) {
            int idx = (seg * 64 + i) * NCH_ + bkt;
            int tmp = lcnt[idx];
            lcnt[idx] = run;
            run += tmp;
        }
        segtot[bkt][seg] = run;
    }
    __syncthreads();
    if (t < NCH_) {
        int run = 0;
#pragma unroll
        for (int s = 0; s < 8; ++s) { int tmp = segtot[t][s]; segtot[t][s] = run; run += tmp; }
        tot[t] = run;
    }
    __syncthreads();
    if (t == 0) {
        int run = 0;
#pragma unroll
        for (int c = 0; c < NCH_; ++c) { bbase[c] = run; run += tot[c]; }
        bbase[NCH_] = run;
#pragma unroll
        for (int c = 0; c <= NCH_; ++c) chunkstart[c] = bbase[c];
    }
    __syncthreads();
    if (t < NCH_ * 8) {
        int bkt = t >> 3, seg = t & 7;
        int add = segtot[bkt][seg];
        for (int i = 0; i < 64; ++i) lcnt[(seg * 64 + i) * NCH_ + bkt] += add;
    }
    __syncthreads();

    for (int p = t; p < NPAIR_; p += 512) {
        int id = ids[p];
        if (id == 0) continue;
        int bkt = id / CHUNK_;
        int pos = bbase[bkt] + lcnt[t * NCH_ + bkt];
        lcnt[t * NCH_ + bkt] += 1;
        float2 o = ocs[p];
        float4 m;
        m.x = __int_as_float(id);
        m.y = __int_as_float(p);
        m.z = o.x;
        m.w = o.y;
        smeta[pos] = m;
    }
}

// ---------------------------------------------------------------------------
// pair body: bit-identical arithmetic to the passing rounds
// ---------------------------------------------------------------------------
__device__ __forceinline__ void pair_body(const float4 m, const float2* __restrict__ sb,
                                          int lo, float* __restrict__ pcontrib) {
    int id  = __float_as_int(m.x);
    int dst = __float_as_int(m.y);
    float2 g = sb[id - lo];
    float wabs = sqrtf(__fadd_rn(__fmul_rn(g.x, g.x), __fmul_rn(g.y, g.y)));
    float pre = __fadd_rn(__fmul_rn(g.x, m.z), __fmul_rn(g.y, m.w));
    float pim = __fsub_rn(__fmul_rn(g.y, m.z), __fmul_rn(g.x, m.w));
    if (pre < 1e-10f && pre > -1e-10f) pre = 1e-10f;
    if (pim < 1e-10f && pim > -1e-10f) pim = 1e-10f;
    float ang = fabsf(atan2f(pim, pre));
    pcontrib[dst] = __fadd_rn(wabs, ang);
}

// ---------------------------------------------------------------------------
// Kernel B: persistent; block bid owns k in [bid*16, bid*16+16). 3-deep
// counted-vmcnt staging pipeline (T3+T4), raw barriers, smeta reg-prefetch.
// ---------------------------------------------------------------------------
__global__ __launch_bounds__(PFTH_, 1) void pf_kernel(const float2* __restrict__ W2,
                                                      const float4* __restrict__ smeta,
                                                      const int* __restrict__ chunkstart,
                                                      float* __restrict__ pfT) {
    extern __shared__ char smem[];
    float*  pcontrib = (float*)smem;                       // [NPAIR_]
    float2* sbuf     = (float2*)(smem + PCON_BYTES_);      // [4][CHUNK_]
    __shared__ int cstart[NCH_ + 1];

    const int t  = threadIdx.x;
    const int wv = t >> 6;
    const int kbase = blockIdx.x * KPB_;
    const float2* Wblk = W2 + (size_t)kbase * VOCAB_;

    if (t <= NCH_) cstart[t] = chunkstart[t];
    __syncthreads();

    auto stageg = [&](int g) {
        int kk = g / NCH_, cc = g % NCH_;
        int base = cc * CHUNK_;
        int rem = VOCAB_ - base;
        int n16 = ((rem < CHUNK_ ? rem : CHUNK_) + 1) >> 1;   // 16B units (1024 or 925)
        int e = (t < n16) ? t : (n16 - 1);                    // clamp: uniform vmcnt, no OOB
        const char* gsrc = (const char*)(Wblk + (size_t)kk * VOCAB_ + base) + (size_t)e * 16;
        char* ldst = (char*)sbuf + (size_t)(g & 3) * (CHUNK_ * 8) + (size_t)(wv * 64) * 16;
        __builtin_amdgcn_global_load_lds((const __attribute__((address_space(1))) void*)gsrc,
                                         (__attribute__((address_space(3))) void*)ldst,
                                         16, 0, 0);
    };

    float4 A0{}, A1{}, B0{}, B1{};
    int AS = 0, AE = 0, BS = 0, BE = 0;

    // prologue: stages first, then smeta prefetch (one-time full drain at g=0 ok)
    stageg(0); stageg(1); stageg(2);
    AS = cstart[0]; AE = cstart[1];
    { int p0 = AS + t;          if (p0 < AE) A0 = smeta[p0];
      int p1 = AS + PFTH_ + t;  if (p1 < AE) A1 = smeta[p1]; }
    for (int i = t; i < NPAIR_; i += PFTH_) pcontrib[i] = 0.0f;

#define PHASE(GG, C0, C1, CS, CE, N0, N1, NS, NE)                                        \
    {                                                                                    \
        const int g_ = (GG);                                                             \
        if (g_ + 3 >= GTOT_) { asm volatile("s_waitcnt vmcnt(0) lgkmcnt(0)" ::: "memory"); } \
        else                 { asm volatile("s_waitcnt vmcnt(3) lgkmcnt(0)" ::: "memory"); } \
        __builtin_amdgcn_s_barrier();                                                    \
        if (g_ + 1 < GTOT_) {                                                            \
            int cc1_ = (g_ + 1) % NCH_;                                                  \
            NS = cstart[cc1_]; NE = cstart[cc1_ + 1];                                    \
            int q0_ = NS + t;          if (q0_ < NE) N0 = smeta[q0_];                    \
            int q1_ = NS + PFTH_ + t;  if (q1_ < NE) N1 = smeta[q1_];                    \
        }                                                                                \
        if (g_ + 3 < GTOT_) stageg(g_ + 3);                                              \
        {                                                                                \
            const float2* sb_ = sbuf + (size_t)(g_ & 3) * CHUNK_;                        \
            const int lo_ = (g_ % NCH_) * CHUNK_;                                        \
            int p0_ = CS + t;          if (p0_ < CE) pair_body(C0, sb_, lo_, pcontrib);  \
            int p1_ = CS + PFTH_ + t;  if (p1_ < CE) pair_body(C1, sb_, lo_, pcontrib);  \
            for (int p_ = CS + 2 * PFTH_ + t; p_ < CE; p_ += PFTH_)                      \
                pair_body(smeta[p_], sb_, lo_, pcontrib);   /* safety, normally empty */ \
        }                                                                                \
        if (g_ % NCH_ == NCH_ - 1) {                                                     \
            asm volatile("s_waitcnt lgkmcnt(0)" ::: "memory");                           \
            __builtin_amdgcn_s_barrier();                                                \
            const int kk_ = g_ / NCH_;                                                   \
            float* outp_ = pfT + (size_t)(kbase + kk_) * B_;                             \
            _Pragma("unroll")                                                            \
            for (int i_ = 0; i_ < B_ / PFTH_; ++i_) {                                    \
                int b_ = i_ * PFTH_ + t;                                                 \
                float acc_ = 0.0f;                                                       \
                _Pragma("unroll")                                                        \
                for (int w_ = 0; w_ < WIN_; ++w_)                                        \
                    acc_ = __fadd_rn(acc_, pcontrib[b_ * WIN_ + w_]);                    \
                outp_[b_] = acc_;                                                        \
            }                                                                            \
        }                                                                                \
    }

    for (int g = 0; g < GTOT_; g += 2) {
        PHASE(g,     A0, A1, AS, AE, B0, B1, BS, BE)
        PHASE(g + 1, B0, B1, BS, BE, A0, A1, AS, AE)
    }
#undef PHASE
}

// ---------------------------------------------------------------------------
// Kernel T: transpose [K,B] -> [B,K] via 64x64 LDS tiles
// ---------------------------------------------------------------------------
__global__ __launch_bounds__(256) void transpose_kb(const float* __restrict__ pfT,
                                                    float* __restrict__ pf) {
    __shared__ float tile[64][65];
    int kb = blockIdx.x * 64;
    int bb = blockIdx.y * 64;
    int tx = threadIdx.x & 63;
    int ty = threadIdx.x >> 6;
#pragma unroll
    for (int i = 0; i < 64; i += 4)
        tile[ty + i][tx] = pfT[(size_t)(kb + ty + i) * B_ + (bb + tx)];
    __syncthreads();
#pragma unroll
    for (int i = 0; i < 64; i += 4)
        pf[(size_t)(bb + ty + i) * K_ + (kb + tx)] = tile[tx][ty + i];
}

// ---------------------------------------------------------------------------
// Kernel C: per-row exact top-64 (radix select, jax tie semantics) + logits
// ---------------------------------------------------------------------------
__global__ __launch_bounds__(256) void topk_logits_kernel(const float* __restrict__ pf,
                                                          const float* __restrict__ w_out,
                                                          const float* __restrict__ b_out,
                                                          float* __restrict__ out) {
    const int b = blockIdx.x;
    const int t = threadIdx.x;
    __shared__ uint32_t srow[K_];
    __shared__ int hist[256];
    __shared__ uint32_t sh_prefix;
    __shared__ int sh_need;
    __shared__ int wave_gt[4], wave_eq[4];
    __shared__ int gt_running, eq_running;
    __shared__ int idxlist[TOPK_];

    const float* rowp = pf + (size_t)b * K_;
    for (int i = t; i < K_; i += 256) srow[i] = __float_as_uint(rowp[i]);
    if (t == 0) { sh_prefix = 0u; sh_need = TOPK_; gt_running = 0; eq_running = 0; }
    __syncthreads();

    for (int pass = 0; pass < 4; ++pass) {
        int shift = 24 - 8 * pass;
        uint32_t himask = (pass == 0) ? 0u : (0xFFFFFFFFu << (shift + 8));
        hist[t] = 0;
        __syncthreads();
        uint32_t prefix = sh_prefix;
        for (int i = t; i < K_; i += 256) {
            uint32_t u = srow[i];
            if ((u & himask) == prefix) atomicAdd(&hist[(u >> shift) & 255], 1);
        }
        __syncthreads();
        if (t == 0) {
            int need = sh_need, cum = 0, bin = 255;
            for (; bin >= 0; --bin) {
                int c = hist[bin];
                if (cum + c >= need) { sh_need = need - cum; break; }
                cum += c;
            }
            sh_prefix = prefix | ((uint32_t)bin << shift);
        }
        __syncthreads();
    }
    const uint32_t T = sh_prefix;
    const int r = sh_need;
    const int c_gt = TOPK_ - r;

    for (int cbase = 0; cbase < K_; cbase += 256) {
        uint32_t u = srow[cbase + t];
        bool gt = (u > T);
        bool eq = (u == T);
        unsigned long long mg = __ballot(gt);
        unsigned long long me = __ballot(eq);
        int lane = t & 63, wv = t >> 6;
        if (lane == 0) { wave_gt[wv] = __popcll(mg); wave_eq[wv] = __popcll(me); }
        __syncthreads();
        int offg = gt_running, offe = eq_running;
        for (int w2 = 0; w2 < wv; ++w2) { offg += wave_gt[w2]; offe += wave_eq[w2]; }
        unsigned long long lmask = (lane == 0) ? 0ull : ((~0ull) >> (64 - lane));
        int rkg = offg + __popcll(mg & lmask);
        int rke = offe + __popcll(me & lmask);
        if (gt) idxlist[rkg] = cbase + t;
        else if (eq && rke < r) idxlist[c_gt + rke] = cbase + t;
        __syncthreads();
        if (t == 0) {
            gt_running += wave_gt[0] + wave_gt[1] + wave_gt[2] + wave_gt[3];
            eq_running += wave_eq[0] + wave_eq[1] + wave_eq[2] + wave_eq[3];
        }
        __syncthreads();
    }

    if (t < NOUT_) {
        float s = b_out[t];
        const float* wrow = w_out + (size_t)t * K_;
#pragma unroll 8
        for (int j = 0; j < TOPK_; ++j) s += wrow[idxlist[j]];
        out[b * NOUT_ + t] = s;
    }
}

// ---------------------------------------------------------------------------
extern "C" void kernel_launch(void* const* d_in, const int* in_sizes, int n_in,
                              void* d_out, int out_size, void* d_ws, size_t ws_size,
                              hipStream_t stream) {
    const int*   ids   = (const int*)d_in[0];
    const float* W     = (const float*)d_in[1];
    const float* w_out = (const float*)d_in[2];
    const float* b_out = (const float*)d_in[3];
    float* out = (float*)d_out;

    char* ws = (char*)d_ws;
    const size_t pf_bytes = (size_t)K_ * B_ * sizeof(float);   // 33.55 MB
    float*  pfT   = (float*)(ws);                              // [K, B]
    float*  pf    = (float*)(ws + pf_bytes);                   // [B, K]
    float2* ocs   = (float2*)(ws + 2 * pf_bytes);              // [NPAIR_] (180 KB)
    float4* smeta = (float4*)(ws + 2 * pf_bytes + 256 * 1024); // [NPAIR_] (360 KB)
    int* chunkstart = (int*)(ws + 2 * pf_bytes + 768 * 1024);  // [NCH_+1]

    (void)hipFuncSetAttribute((const void*)pf_kernel,
                              hipFuncAttributeMaxDynamicSharedMemorySize,
                              SMEM_BYTES_);

    prep_kernel<<<(B_ + 255) / 256, 256, 0, stream>>>(ids, ocs);
    bucket_kernel<<<1, 512, 0, stream>>>(ids, ocs, smeta, chunkstart);
    pf_kernel<<<NBLK_, PFTH_, SMEM_BYTES_, stream>>>((const float2*)W, smeta, chunkstart, pfT);
    transpose_kb<<<dim3(K_ / 64, B_ / 64), 256, 0, stream>>>(pfT, pf);
    topk_logits_kernel<<<B_, 256, 0, stream>>>(pf, w_out, b_out, out);
}

// Round 5
// 470.882 us; speedup vs baseline: 1.1940x; 1.1940x over previous
//
#include <hip/hip_runtime.h>
#include <hip/hip_bf16.h>
#include <stdint.h>

#define B_     2048
#define WIN_   11
#define K_     4096
#define VOCAB_ 30522
#define NOUT_  18
#define TOPK_  64
#define NPAIR_ (B_ * WIN_)         /* 22528 */
#define PI_F   3.14159274101257324f

#define NCH_    15                 /* chunks per k-slice */
#define CHUNK_  2048               /* entries; 16 KB; exactly 1 global_load_lds/thread */
#define KPB_    16                 /* k per persistent block */
#define NBLK_   (K_ / KPB_)        /* 256 blocks = 1 per CU */
#define GTOT_   (NCH_ * KPB_)      /* 240 phases; divisible by 3 */
#define PFTH_   1024
#define PCON_BYTES_ (NPAIR_ * 4)                    /* 90112 */
#define SMEM_BYTES_ (PCON_BYTES_ + 4 * CHUNK_ * 8)  /* 155648 <= 160 KiB */

static_assert(GTOT_ % 3 == 0, "rotation needs GTOT % 3 == 0");

// ---------------------------------------------------------------------------
// Kernel A: per-batch window prep -> cos/sin per (b,w)
// ---------------------------------------------------------------------------
__global__ void prep_kernel(const int* __restrict__ ids, float2* __restrict__ ocs) {
    int b = blockIdx.x * blockDim.x + threadIdx.x;
    if (b >= B_) return;
    const int* row = ids + b * WIN_;
    int poss[WIN_];
    int cnt = 0;
#pragma unroll
    for (int w = 0; w < WIN_; ++w) { cnt += (row[w] != 0); poss[w] = cnt; }
    float fsl = (float)((cnt > 0) ? cnt : WIN_);
#pragma unroll
    for (int w = 0; w < WIN_; ++w) {
        float pos = __fdiv_rn(__fmul_rn(PI_F, (float)poss[w]), fsl);
        float2 o;
        o.x = cosf(pos);
        o.y = sinf(pos);
        ocs[b * WIN_ + w] = o;
    }
}

// ---------------------------------------------------------------------------
// Kernel A2: stable deterministic bucket-by-chunk of the 22528 (b,w) pairs.
// smeta[pos] = {id, pairidx, cos, sin}; chunkstart[0..NCH_].
// ---------------------------------------------------------------------------
__global__ __launch_bounds__(512) void bucket_kernel(const int* __restrict__ ids,
                                                     const float2* __restrict__ ocs,
                                                     float4* __restrict__ smeta,
                                                     int* __restrict__ chunkstart) {
    __shared__ int lcnt[512 * NCH_];
    __shared__ int segtot[NCH_][8];
    __shared__ int tot[NCH_];
    __shared__ int bbase[NCH_ + 1];
    const int t = threadIdx.x;

#pragma unroll
    for (int c = 0; c < NCH_; ++c) lcnt[t * NCH_ + c] = 0;
    __syncthreads();

    for (int p = t; p < NPAIR_; p += 512) {
        int id = ids[p];
        if (id != 0) lcnt[t * NCH_ + (id / CHUNK_)] += 1;
    }
    __syncthreads();

    if (t < NCH_ * 8) {
        int bkt = t >> 3, seg = t & 7;
        int run = 0;
        for (int i = 0; i < 64; ++i) {
            int idx = (seg * 64 + i) * NCH_ + bkt;
            int tmp = lcnt[idx];
            lcnt[idx] = run;
            run += tmp;
        }
        segtot[bkt][seg] = run;
    }
    __syncthreads();
    if (t < NCH_) {
        int run = 0;
#pragma unroll
        for (int s = 0; s < 8; ++s) { int tmp = segtot[t][s]; segtot[t][s] = run; run += tmp; }
        tot[t] = run;
    }
    __syncthreads();
    if (t == 0) {
        int run = 0;
#pragma unroll
        for (int c = 0; c < NCH_; ++c) { bbase[c] = run; run += tot[c]; }
        bbase[NCH_] = run;
#pragma unroll
        for (int c = 0; c <= NCH_; ++c) chunkstart[c] = bbase[c];
    }
    __syncthreads();
    if (t < NCH_ * 8) {
        int bkt = t >> 3, seg = t & 7;
        int add = segtot[bkt][seg];
        for (int i = 0; i < 64; ++i) lcnt[(seg * 64 + i) * NCH_ + bkt] += add;
    }
    __syncthreads();

    for (int p = t; p < NPAIR_; p += 512) {
        int id = ids[p];
        if (id == 0) continue;
        int bkt = id / CHUNK_;
        int pos = bbase[bkt] + lcnt[t * NCH_ + bkt];
        lcnt[t * NCH_ + bkt] += 1;
        float2 o = ocs[p];
        float4 m;
        m.x = __int_as_float(id);
        m.y = __int_as_float(p);
        m.z = o.x;
        m.w = o.y;
        smeta[pos] = m;
    }
}

// ---------------------------------------------------------------------------
// pair body: bit-identical arithmetic to the passing rounds
// ---------------------------------------------------------------------------
__device__ __forceinline__ void pair_body(const float4 m, const float2* __restrict__ sb,
                                          int lo, float* __restrict__ pcontrib) {
    int id  = __float_as_int(m.x);
    int dst = __float_as_int(m.y);
    float2 g = sb[id - lo];
    float wabs = sqrtf(__fadd_rn(__fmul_rn(g.x, g.x), __fmul_rn(g.y, g.y)));
    float pre = __fadd_rn(__fmul_rn(g.x, m.z), __fmul_rn(g.y, m.w));
    float pim = __fsub_rn(__fmul_rn(g.y, m.z), __fmul_rn(g.x, m.w));
    if (pre < 1e-10f && pre > -1e-10f) pre = 1e-10f;
    if (pim < 1e-10f && pim > -1e-10f) pim = 1e-10f;
    float ang = fabsf(atan2f(pim, pre));
    pcontrib[dst] = __fadd_rn(wabs, ang);
}

// ---------------------------------------------------------------------------
// Kernel B: persistent, 1 block/CU, block owns k in [bid*16, bid*16+16).
// 3-deep stage pipeline + 2-phase-ahead smeta register prefetch (3-rotation).
// All per-phase VM ops unconditional (clamped) -> wave-uniform vmcnt counts.
// Entry wait vmcnt(4) retires exactly the oldest phase-triple {sm ab, st}.
// ---------------------------------------------------------------------------
__global__ __launch_bounds__(PFTH_, 1) void pf_kernel(const float2* __restrict__ W2,
                                                      const float4* __restrict__ smeta,
                                                      const int* __restrict__ chunkstart,
                                                      float* __restrict__ pfT) {
    extern __shared__ char smem[];
    float*  pcontrib = (float*)smem;                       // [NPAIR_]
    float2* sbuf     = (float2*)(smem + PCON_BYTES_);      // [4][CHUNK_]
    __shared__ int cstart[NCH_ + 1];

    const int t  = threadIdx.x;
    const int wv = t >> 6;
    const int kbase = blockIdx.x * KPB_;
    const float2* Wblk = W2 + (size_t)kbase * VOCAB_;

    if (t <= NCH_) cstart[t] = chunkstart[t];
    __syncthreads();

    auto stageg = [&](int gph) {
        int gp = (gph < GTOT_) ? gph : (GTOT_ - 1);        // tail: re-stage same data (benign)
        int kk = gp / NCH_, cc = gp % NCH_;
        int base = cc * CHUNK_;
        int rem = VOCAB_ - base;
        int n16 = ((rem < CHUNK_ ? rem : CHUNK_) + 1) >> 1;
        int e = (t < n16) ? t : (n16 - 1);                 // clamp: uniform vmcnt, no OOB
        const char* gsrc = (const char*)(Wblk + (size_t)kk * VOCAB_ + base) + (size_t)e * 16;
        char* ldst = (char*)sbuf + (size_t)(gp & 3) * (CHUNK_ * 8) + (size_t)(wv * 64) * 16;
        __builtin_amdgcn_global_load_lds((const __attribute__((address_space(1))) void*)gsrc,
                                         (__attribute__((address_space(3))) void*)ldst,
                                         16, 0, 0);
    };

    float4 r0a, r0b, r1a, r1b, r2a, r2b;
    int S0, E0, S1, E1, S2, E2;

    // prologue: fill sets 0,1 (chunks 0,1), stage phases 0..2, init pcontrib, full drain
    stageg(0);
    { S0 = cstart[0]; E0 = cstart[1];
      int q0 = S0 + t;          if (q0 > NPAIR_ - 1) q0 = NPAIR_ - 1;
      int q1 = S0 + PFTH_ + t;  if (q1 > NPAIR_ - 1) q1 = NPAIR_ - 1;
      r0a = smeta[q0]; r0b = smeta[q1]; }
    stageg(1);
    { S1 = cstart[1]; E1 = cstart[2];
      int q0 = S1 + t;          if (q0 > NPAIR_ - 1) q0 = NPAIR_ - 1;
      int q1 = S1 + PFTH_ + t;  if (q1 > NPAIR_ - 1) q1 = NPAIR_ - 1;
      r1a = smeta[q0]; r1b = smeta[q1]; }
    stageg(2);
    for (int i = t; i < NPAIR_; i += PFTH_) pcontrib[i] = 0.0f;
    asm volatile("s_waitcnt vmcnt(0) lgkmcnt(0)" ::: "memory");
    __builtin_amdgcn_s_barrier();
    __builtin_amdgcn_sched_barrier(0);

#define PHASE(GG, CA, CB, CS, CE, NA, NB, NS, NE)                                \
    {                                                                            \
        const int g_ = (GG);                                                     \
        asm volatile("s_waitcnt vmcnt(4)" ::: "memory");                         \
        __builtin_amdgcn_s_barrier();                                            \
        __builtin_amdgcn_sched_barrier(0);                                       \
        {   int c2_ = (g_ + 2) % NCH_;                                           \
            NS = cstart[c2_]; NE = cstart[c2_ + 1];                              \
            int q0_ = NS + t;         if (q0_ > NPAIR_ - 1) q0_ = NPAIR_ - 1;    \
            int q1_ = NS + PFTH_ + t; if (q1_ > NPAIR_ - 1) q1_ = NPAIR_ - 1;    \
            NA = smeta[q0_]; NB = smeta[q1_];                                    \
            stageg(g_ + 3); }                                                    \
        __builtin_amdgcn_sched_barrier(0);                                       \
        {   const float2* sb_ = sbuf + (size_t)(g_ & 3) * CHUNK_;                \
            const int lo_ = (g_ % NCH_) * CHUNK_;                                \
            if (CS + t < CE)          pair_body(CA, sb_, lo_, pcontrib);         \
            if (CS + PFTH_ + t < CE)  pair_body(CB, sb_, lo_, pcontrib);         \
            for (int p_ = CS + 2 * PFTH_ + t; p_ < CE; p_ += PFTH_)              \
                pair_body(smeta[p_], sb_, lo_, pcontrib); }                      \
        if (g_ % NCH_ == NCH_ - 1) {                                             \
            asm volatile("s_waitcnt lgkmcnt(0)" ::: "memory");                   \
            __builtin_amdgcn_s_barrier();                                        \
            __builtin_amdgcn_sched_barrier(0);                                   \
            const int kk_ = g_ / NCH_;                                           \
            float* outp_ = pfT + (size_t)(kbase + kk_) * B_;                     \
            _Pragma("unroll")                                                    \
            for (int i_ = 0; i_ < B_ / PFTH_; ++i_) {                            \
                int b_ = i_ * PFTH_ + t;                                         \
                float acc_ = 0.0f;                                               \
                _Pragma("unroll")                                                \
                for (int w_ = 0; w_ < WIN_; ++w_)                                \
                    acc_ = __fadd_rn(acc_, pcontrib[b_ * WIN_ + w_]);            \
                outp_[b_] = acc_;                                                \
            }                                                                    \
        }                                                                        \
    }

#pragma unroll 1
    for (int g = 0; g < GTOT_; g += 3) {
        PHASE(g,     r0a, r0b, S0, E0, r2a, r2b, S2, E2)
        PHASE(g + 1, r1a, r1b, S1, E1, r0a, r0b, S0, E0)
        PHASE(g + 2, r2a, r2b, S2, E2, r1a, r1b, S1, E1)
    }
#undef PHASE
}

// ---------------------------------------------------------------------------
// Kernel T: transpose [K,B] -> [B,K] via 64x64 LDS tiles
// ---------------------------------------------------------------------------
__global__ __launch_bounds__(256) void transpose_kb(const float* __restrict__ pfT,
                                                    float* __restrict__ pf) {
    __shared__ float tile[64][65];
    int kb = blockIdx.x * 64;
    int bb = blockIdx.y * 64;
    int tx = threadIdx.x & 63;
    int ty = threadIdx.x >> 6;
#pragma unroll
    for (int i = 0; i < 64; i += 4)
        tile[ty + i][tx] = pfT[(size_t)(kb + ty + i) * B_ + (bb + tx)];
    __syncthreads();
#pragma unroll
    for (int i = 0; i < 64; i += 4)
        pf[(size_t)(bb + ty + i) * K_ + (kb + tx)] = tile[tx][ty + i];
}

// ---------------------------------------------------------------------------
// Kernel C: per-row exact top-64 (radix select, jax tie semantics) + logits
// ---------------------------------------------------------------------------
__global__ __launch_bounds__(256) void topk_logits_kernel(const float* __restrict__ pf,
                                                          const float* __restrict__ w_out,
                                                          const float* __restrict__ b_out,
                                                          float* __restrict__ out) {
    const int b = blockIdx.x;
    const int t = threadIdx.x;
    __shared__ uint32_t srow[K_];
    __shared__ int hist[256];
    __shared__ uint32_t sh_prefix;
    __shared__ int sh_need;
    __shared__ int wave_gt[4], wave_eq[4];
    __shared__ int gt_running, eq_running;
    __shared__ int idxlist[TOPK_];
    __shared__ float partial[4][NOUT_];

    const float* rowp = pf + (size_t)b * K_;
    for (int i = t; i < K_; i += 256) srow[i] = __float_as_uint(rowp[i]);
    if (t == 0) { sh_prefix = 0u; sh_need = TOPK_; gt_running = 0; eq_running = 0; }
    __syncthreads();

    for (int pass = 0; pass < 4; ++pass) {
        int shift = 24 - 8 * pass;
        uint32_t himask = (pass == 0) ? 0u : (0xFFFFFFFFu << (shift + 8));
        hist[t] = 0;
        __syncthreads();
        uint32_t prefix = sh_prefix;
        for (int i = t; i < K_; i += 256) {
            uint32_t u = srow[i];
            if ((u & himask) == prefix) atomicAdd(&hist[(u >> shift) & 255], 1);
        }
        __syncthreads();
        if (t == 0) {
            int need = sh_need, cum = 0, bin = 255;
            for (; bin >= 0; --bin) {
                int c = hist[bin];
                if (cum + c >= need) { sh_need = need - cum; break; }
                cum += c;
            }
            sh_prefix = prefix | ((uint32_t)bin << shift);
        }
        __syncthreads();
    }
    const uint32_t T = sh_prefix;
    const int r = sh_need;
    const int c_gt = TOPK_ - r;

    for (int cbase = 0; cbase < K_; cbase += 256) {
        uint32_t u = srow[cbase + t];
        bool gt = (u > T);
        bool eq = (u == T);
        unsigned long long mg = __ballot(gt);
        unsigned long long me = __ballot(eq);
        int lane = t & 63, wv = t >> 6;
        if (lane == 0) { wave_gt[wv] = __popcll(mg); wave_eq[wv] = __popcll(me); }
        __syncthreads();
        int offg = gt_running, offe = eq_running;
        for (int w2 = 0; w2 < wv; ++w2) { offg += wave_gt[w2]; offe += wave_eq[w2]; }
        unsigned long long lmask = (lane == 0) ? 0ull : ((~0ull) >> (64 - lane));
        int rkg = offg + __popcll(mg & lmask);
        int rke = offe + __popcll(me & lmask);
        if (gt) idxlist[rkg] = cbase + t;
        else if (eq && rke < r) idxlist[c_gt + rke] = cbase + t;
        __syncthreads();
        if (t == 0) {
            gt_running += wave_gt[0] + wave_gt[1] + wave_gt[2] + wave_gt[3];
            eq_running += wave_eq[0] + wave_eq[1] + wave_eq[2] + wave_eq[3];
        }
        __syncthreads();
    }

    // logits: 4 waves each sum 16 of the 64 selected columns, then combine
    {
        int lane = t & 63, wv4 = t >> 6;
        if (lane < NOUT_) {
            const float* wrow = w_out + (size_t)lane * K_;
            float s = 0.0f;
#pragma unroll
            for (int j = 0; j < TOPK_ / 4; ++j) s += wrow[idxlist[wv4 * (TOPK_ / 4) + j]];
            partial[wv4][lane] = s;
        }
        __syncthreads();
        if (t < NOUT_) {
            float s = b_out[t] + partial[0][t] + partial[1][t] + partial[2][t] + partial[3][t];
            out[b * NOUT_ + t] = s;
        }
    }
}

// ---------------------------------------------------------------------------
extern "C" void kernel_launch(void* const* d_in, const int* in_sizes, int n_in,
                              void* d_out, int out_size, void* d_ws, size_t ws_size,
                              hipStream_t stream) {
    const int*   ids   = (const int*)d_in[0];
    const float* W     = (const float*)d_in[1];
    const float* w_out = (const float*)d_in[2];
    const float* b_out = (const float*)d_in[3];
    float* out = (float*)d_out;

    char* ws = (char*)d_ws;
    const size_t pf_bytes = (size_t)K_ * B_ * sizeof(float);   // 33.55 MB
    float*  pfT   = (float*)(ws);                              // [K, B]
    float*  pf    = (float*)(ws + pf_bytes);                   // [B, K]
    float2* ocs   = (float2*)(ws + 2 * pf_bytes);              // [NPAIR_] (180 KB)
    float4* smeta = (float4*)(ws + 2 * pf_bytes + 256 * 1024); // [NPAIR_] (360 KB)
    int* chunkstart = (int*)(ws + 2 * pf_bytes + 768 * 1024);  // [NCH_+1]

    (void)hipFuncSetAttribute((const void*)pf_kernel,
                              hipFuncAttributeMaxDynamicSharedMemorySize,
                              SMEM_BYTES_);

    prep_kernel<<<(B_ + 255) / 256, 256, 0, stream>>>(ids, ocs);
    bucket_kernel<<<1, 512, 0, stream>>>(ids, ocs, smeta, chunkstart);
    pf_kernel<<<NBLK_, PFTH_, SMEM_BYTES_, stream>>>((const float2*)W, smeta, chunkstart, pfT);
    transpose_kb<<<dim3(K_ / 64, B_ / 64), 256, 0, stream>>>(pfT, pf);
    topk_logits_kernel<<<B_, 256, 0, stream>>>(pf, w_out, b_out, out);
}

// Round 6
// 448.761 us; speedup vs baseline: 1.2528x; 1.0493x over previous
//
#include <hip/hip_runtime.h>
#include <hip/hip_bf16.h>
#include <stdint.h>

#define B_     2048
#define WIN_   11
#define K_     4096
#define VOCAB_ 30522
#define NOUT_  18
#define TOPK_  64
#define NPAIR_ (B_ * WIN_)         /* 22528 */
#define PI_F   3.14159274101257324f

#define NCH_    15                 /* chunks per k-slice */
#define CHUNK_  2048               /* entries = 16 KB = 1024 float4 units */
#define UNITS_  1024               /* float4 units per full chunk */
#define UPK_    15261              /* float4 units per k-slice (30522/2) */
#define TAILU_  925                /* units in last chunk (1850 entries) */
#define KPB_    16                 /* k per persistent block */
#define NBLK_   (K_ / KPB_)        /* 256 blocks = 1 per CU */
#define GTOT_   (NCH_ * KPB_)      /* 240 phases; % 4 == 0 */
#define PFTH_   1024
#define PCON_BYTES_ (NPAIR_ * 4)                    /* 90112 */
#define SMEM_BYTES_ (PCON_BYTES_ + 4 * CHUNK_ * 8)  /* 155648 (proven) */

static_assert(GTOT_ % 4 == 0, "4-rotation needs GTOT % 4 == 0");

// ---------------------------------------------------------------------------
// Kernel A: per-batch window prep -> cos/sin per (b,w)
// ---------------------------------------------------------------------------
__global__ void prep_kernel(const int* __restrict__ ids, float2* __restrict__ ocs) {
    int b = blockIdx.x * blockDim.x + threadIdx.x;
    if (b >= B_) return;
    const int* row = ids + b * WIN_;
    int poss[WIN_];
    int cnt = 0;
#pragma unroll
    for (int w = 0; w < WIN_; ++w) { cnt += (row[w] != 0); poss[w] = cnt; }
    float fsl = (float)((cnt > 0) ? cnt : WIN_);
#pragma unroll
    for (int w = 0; w < WIN_; ++w) {
        float pos = __fdiv_rn(__fmul_rn(PI_F, (float)poss[w]), fsl);
        float2 o;
        o.x = cosf(pos);
        o.y = sinf(pos);
        ocs[b * WIN_ + w] = o;
    }
}

// ---------------------------------------------------------------------------
// Kernel A2: stable deterministic bucket-by-chunk of the 22528 (b,w) pairs.
// smeta[pos] = {id, pairidx, cos, sin}; chunkstart[0..NCH_].
// ---------------------------------------------------------------------------
__global__ __launch_bounds__(512) void bucket_kernel(const int* __restrict__ ids,
                                                     const float2* __restrict__ ocs,
                                                     float4* __restrict__ smeta,
                                                     int* __restrict__ chunkstart) {
    __shared__ int lcnt[512 * NCH_];
    __shared__ int segtot[NCH_][8];
    __shared__ int tot[NCH_];
    __shared__ int bbase[NCH_ + 1];
    const int t = threadIdx.x;

#pragma unroll
    for (int c = 0; c < NCH_; ++c) lcnt[t * NCH_ + c] = 0;
    __syncthreads();

    for (int p = t; p < NPAIR_; p += 512) {
        int id = ids[p];
        if (id != 0) lcnt[t * NCH_ + (id / CHUNK_)] += 1;
    }
    __syncthreads();

    if (t < NCH_ * 8) {
        int bkt = t >> 3, seg = t & 7;
        int run = 0;
        for (int i = 0; i < 64; ++i) {
            int idx = (seg * 64 + i) * NCH_ + bkt;
            int tmp = lcnt[idx];
            lcnt[idx] = run;
            run += tmp;
        }
        segtot[bkt][seg] = run;
    }
    __syncthreads();
    if (t < NCH_) {
        int run = 0;
#pragma unroll
        for (int s = 0; s < 8; ++s) { int tmp = segtot[t][s]; segtot[t][s] = run; run += tmp; }
        tot[t] = run;
    }
    __syncthreads();
    if (t == 0) {
        int run = 0;
#pragma unroll
        for (int c = 0; c < NCH_; ++c) { bbase[c] = run; run += tot[c]; }
        bbase[NCH_] = run;
#pragma unroll
        for (int c = 0; c <= NCH_; ++c) chunkstart[c] = bbase[c];
    }
    __syncthreads();
    if (t < NCH_ * 8) {
        int bkt = t >> 3, seg = t & 7;
        int add = segtot[bkt][seg];
        for (int i = 0; i < 64; ++i) lcnt[(seg * 64 + i) * NCH_ + bkt] += add;
    }
    __syncthreads();

    for (int p = t; p < NPAIR_; p += 512) {
        int id = ids[p];
        if (id == 0) continue;
        int bkt = id / CHUNK_;
        int pos = bbase[bkt] + lcnt[t * NCH_ + bkt];
        lcnt[t * NCH_ + bkt] += 1;
        float2 o = ocs[p];
        float4 m;
        m.x = __int_as_float(id);
        m.y = __int_as_float(p);
        m.z = o.x;
        m.w = o.y;
        smeta[pos] = m;
    }
}

// ---------------------------------------------------------------------------
// pair body: bit-identical arithmetic to the passing rounds
// ---------------------------------------------------------------------------
__device__ __forceinline__ void pair_body(const float4 m, const float2* __restrict__ sb,
                                          int lo, float* __restrict__ pcontrib) {
    int id  = __float_as_int(m.x);
    int dst = __float_as_int(m.y);
    float2 g = sb[id - lo];
    float wabs = sqrtf(__fadd_rn(__fmul_rn(g.x, g.x), __fmul_rn(g.y, g.y)));
    float pre = __fadd_rn(__fmul_rn(g.x, m.z), __fmul_rn(g.y, m.w));
    float pim = __fsub_rn(__fmul_rn(g.y, m.z), __fmul_rn(g.x, m.w));
    if (pre < 1e-10f && pre > -1e-10f) pre = 1e-10f;
    if (pim < 1e-10f && pim > -1e-10f) pim = 1e-10f;
    float ang = fabsf(atan2f(pim, pre));
    pcontrib[dst] = __fadd_rn(wabs, ang);
}

// ---------------------------------------------------------------------------
// Kernel B: persistent, 1 block/CU. REGISTER-staged W (global->VGPR 4-deep,
// ds_write 1-ahead): all load deps are register-visible so the compiler emits
// exact counted vmcnt waits. Barriers drain lgkm ONLY (never vmcnt) so the
// 4-chunk (64 KB/CU) load pipeline survives barriers.
// ---------------------------------------------------------------------------
__global__ __launch_bounds__(PFTH_, 1) void pf_kernel(const float4* __restrict__ W4,
                                                      const float4* __restrict__ smeta,
                                                      const int* __restrict__ chunkstart,
                                                      float* __restrict__ pfT) {
    extern __shared__ char smem[];
    float*  pcontrib = (float*)smem;                       // [NPAIR_]
    float2* sbuf     = (float2*)(smem + PCON_BYTES_);      // [4][CHUNK_]
    __shared__ int cstart[NCH_ + 1];

    const int t = threadIdx.x;
    const int kbase = blockIdx.x * KPB_;

    if (t <= NCH_) cstart[t] = chunkstart[t];
    __syncthreads();

    float4 w0, w1, w2, w3;
    float4 sA0, sA1, sB0, sB1;

    // ---- prologue: load chunks 0..3 to regs, smeta(ch0) to sA, write ch0
    {
        const float4* Wb = W4 + (size_t)kbase * UPK_;
        w0 = Wb[0 * UNITS_ + t];
        w1 = Wb[1 * UNITS_ + t];
        w2 = Wb[2 * UNITS_ + t];
        w3 = Wb[3 * UNITS_ + t];
        int q0 = t;          if (q0 > NPAIR_ - 1) q0 = NPAIR_ - 1;
        int q1 = PFTH_ + t;  if (q1 > NPAIR_ - 1) q1 = NPAIR_ - 1;
        sA0 = smeta[q0];
        sA1 = smeta[q1];
        ((float4*)sbuf)[t] = w0;                 // buf0 <- chunk 0 (auto vmcnt wait)
        for (int i = t; i < NPAIR_; i += PFTH_) pcontrib[i] = 0.0f;
    }

#define PHASE(J, WLD, WWR, SU0, SU1, SL0, SL1)                                   \
    {                                                                            \
        const int p_ = g + (J);                                                  \
        /* entry: lgkm-only drain + raw barrier (vmcnt pipeline survives) */     \
        __builtin_amdgcn_sched_barrier(0);                                       \
        asm volatile("s_waitcnt lgkmcnt(0)" ::: "memory");                       \
        __builtin_amdgcn_s_barrier();                                            \
        __builtin_amdgcn_sched_barrier(0);                                       \
        int ccj_ = cc + (J); int kkj_ = kk;                                      \
        if (ccj_ >= NCH_) { ccj_ -= NCH_; kkj_ += 1; }                           \
        /* smeta prefetch for chunk p+1 (ping-pong set) */                       \
        {   int cn_ = ccj_ + 1; if (cn_ >= NCH_) cn_ = 0;                        \
            int ns_ = cstart[cn_];                                               \
            int q0_ = ns_ + t;          if (q0_ > NPAIR_ - 1) q0_ = NPAIR_ - 1;  \
            int q1_ = ns_ + PFTH_ + t;  if (q1_ > NPAIR_ - 1) q1_ = NPAIR_ - 1;  \
            SL0 = smeta[q0_]; SL1 = smeta[q1_]; }                                \
        /* W load for chunk p+4 (4-deep) */                                      \
        {   int cl_ = ccj_ + 4; int kl_ = kkj_;                                  \
            if (cl_ >= NCH_) { cl_ -= NCH_; kl_ += 1; }                          \
            if (p_ + 4 >= GTOT_) { cl_ = NCH_ - 1; kl_ = KPB_ - 1; }             \
            int nu_ = (cl_ == NCH_ - 1) ? TAILU_ : UNITS_;                       \
            if (t < nu_)                                                         \
                WLD = W4[(size_t)(kbase + kl_) * UPK_ + cl_ * UNITS_ + t]; }     \
        /* ds_write chunk p+1 from regs loaded 3 phases ago */                   \
        {   int cw_ = ccj_ + 1; if (cw_ >= NCH_) cw_ = 0;                        \
            int nw_ = (cw_ == NCH_ - 1) ? TAILU_ : UNITS_;                       \
            if (t < nw_)                                                         \
                ((float4*)((char*)sbuf + (size_t)((p_ + 1) & 3) * (CHUNK_ * 8)))[t] = WWR; } \
        /* compute chunk p */                                                    \
        {   const float2* sb_ = (const float2*)((char*)sbuf + (size_t)(p_ & 3) * (CHUNK_ * 8)); \
            const int lo_ = ccj_ * CHUNK_;                                       \
            const int cs_ = cstart[ccj_], ce_ = cstart[ccj_ + 1];                \
            if (cs_ + t < ce_)          pair_body(SU0, sb_, lo_, pcontrib);      \
            if (cs_ + PFTH_ + t < ce_)  pair_body(SU1, sb_, lo_, pcontrib);      \
            for (int pp_ = cs_ + 2 * PFTH_ + t; pp_ < ce_; pp_ += PFTH_)         \
                pair_body(smeta[pp_], sb_, lo_, pcontrib); }                     \
        /* k-boundary: sum pcontrib in exact w order -> pfT */                   \
        if (ccj_ == NCH_ - 1) {                                                  \
            __builtin_amdgcn_sched_barrier(0);                                   \
            asm volatile("s_waitcnt lgkmcnt(0)" ::: "memory");                   \
            __builtin_amdgcn_s_barrier();                                        \
            __builtin_amdgcn_sched_barrier(0);                                   \
            float* outp_ = pfT + (size_t)(kbase + kkj_) * B_;                    \
            _Pragma("unroll")                                                    \
            for (int i_ = 0; i_ < B_ / PFTH_; ++i_) {                            \
                int b_ = i_ * PFTH_ + t;                                         \
                float acc_ = 0.0f;                                               \
                _Pragma("unroll")                                                \
                for (int w_ = 0; w_ < WIN_; ++w_)                                \
                    acc_ = __fadd_rn(acc_, pcontrib[b_ * WIN_ + w_]);            \
                outp_[b_] = acc_;                                                \
            }                                                                    \
        }                                                                        \
    }

#pragma unroll 1
    for (int g = 0; g < GTOT_; g += 4) {
        const int cc = g % NCH_, kk = g / NCH_;
        PHASE(0, w0, w1, sA0, sA1, sB0, sB1)
        PHASE(1, w1, w2, sB0, sB1, sA0, sA1)
        PHASE(2, w2, w3, sA0, sA1, sB0, sB1)
        PHASE(3, w3, w0, sB0, sB1, sA0, sA1)
    }
#undef PHASE
}

// ---------------------------------------------------------------------------
// Kernel T: transpose [K,B] -> [B,K] via 64x64 LDS tiles
// ---------------------------------------------------------------------------
__global__ __launch_bounds__(256) void transpose_kb(const float* __restrict__ pfT,
                                                    float* __restrict__ pf) {
    __shared__ float tile[64][65];
    int kb = blockIdx.x * 64;
    int bb = blockIdx.y * 64;
    int tx = threadIdx.x & 63;
    int ty = threadIdx.x >> 6;
#pragma unroll
    for (int i = 0; i < 64; i += 4)
        tile[ty + i][tx] = pfT[(size_t)(kb + ty + i) * B_ + (bb + tx)];
    __syncthreads();
#pragma unroll
    for (int i = 0; i < 64; i += 4)
        pf[(size_t)(bb + ty + i) * K_ + (kb + tx)] = tile[tx][ty + i];
}

// ---------------------------------------------------------------------------
// Kernel C: per-row exact top-64 (radix select, jax tie semantics) + logits
// ---------------------------------------------------------------------------
__global__ __launch_bounds__(256) void topk_logits_kernel(const float* __restrict__ pf,
                                                          const float* __restrict__ w_out,
                                                          const float* __restrict__ b_out,
                                                          float* __restrict__ out) {
    const int b = blockIdx.x;
    const int t = threadIdx.x;
    __shared__ uint32_t srow[K_];
    __shared__ int hist[256];
    __shared__ uint32_t sh_prefix;
    __shared__ int sh_need;
    __shared__ int wave_gt[4], wave_eq[4];
    __shared__ int gt_running, eq_running;
    __shared__ int idxlist[TOPK_];
    __shared__ float partial[4][NOUT_];

    const float* rowp = pf + (size_t)b * K_;
    for (int i = t; i < K_; i += 256) srow[i] = __float_as_uint(rowp[i]);
    if (t == 0) { sh_prefix = 0u; sh_need = TOPK_; gt_running = 0; eq_running = 0; }
    __syncthreads();

    for (int pass = 0; pass < 4; ++pass) {
        int shift = 24 - 8 * pass;
        uint32_t himask = (pass == 0) ? 0u : (0xFFFFFFFFu << (shift + 8));
        hist[t] = 0;
        __syncthreads();
        uint32_t prefix = sh_prefix;
        for (int i = t; i < K_; i += 256) {
            uint32_t u = srow[i];
            if ((u & himask) == prefix) atomicAdd(&hist[(u >> shift) & 255], 1);
        }
        __syncthreads();
        if (t == 0) {
            int need = sh_need, cum = 0, bin = 255;
            for (; bin >= 0; --bin) {
                int c = hist[bin];
                if (cum + c >= need) { sh_need = need - cum; break; }
                cum += c;
            }
            sh_prefix = prefix | ((uint32_t)bin << shift);
        }
        __syncthreads();
    }
    const uint32_t T = sh_prefix;
    const int r = sh_need;
    const int c_gt = TOPK_ - r;

    for (int cbase = 0; cbase < K_; cbase += 256) {
        uint32_t u = srow[cbase + t];
        bool gt = (u > T);
        bool eq = (u == T);
        unsigned long long mg = __ballot(gt);
        unsigned long long me = __ballot(eq);
        int lane = t & 63, wv = t >> 6;
        if (lane == 0) { wave_gt[wv] = __popcll(mg); wave_eq[wv] = __popcll(me); }
        __syncthreads();
        int offg = gt_running, offe = eq_running;
        for (int w2 = 0; w2 < wv; ++w2) { offg += wave_gt[w2]; offe += wave_eq[w2]; }
        unsigned long long lmask = (lane == 0) ? 0ull : ((~0ull) >> (64 - lane));
        int rkg = offg + __popcll(mg & lmask);
        int rke = offe + __popcll(me & lmask);
        if (gt) idxlist[rkg] = cbase + t;
        else if (eq && rke < r) idxlist[c_gt + rke] = cbase + t;
        __syncthreads();
        if (t == 0) {
            gt_running += wave_gt[0] + wave_gt[1] + wave_gt[2] + wave_gt[3];
            eq_running += wave_eq[0] + wave_eq[1] + wave_eq[2] + wave_eq[3];
        }
        __syncthreads();
    }

    {
        int lane = t & 63, wv4 = t >> 6;
        if (lane < NOUT_) {
            const float* wrow = w_out + (size_t)lane * K_;
            float s = 0.0f;
#pragma unroll
            for (int j = 0; j < TOPK_ / 4; ++j) s += wrow[idxlist[wv4 * (TOPK_ / 4) + j]];
            partial[wv4][lane] = s;
        }
        __syncthreads();
        if (t < NOUT_) {
            float s = b_out[t] + partial[0][t] + partial[1][t] + partial[2][t] + partial[3][t];
            out[b * NOUT_ + t] = s;
        }
    }
}

// ---------------------------------------------------------------------------
extern "C" void kernel_launch(void* const* d_in, const int* in_sizes, int n_in,
                              void* d_out, int out_size, void* d_ws, size_t ws_size,
                              hipStream_t stream) {
    const int*   ids   = (const int*)d_in[0];
    const float* W     = (const float*)d_in[1];
    const float* w_out = (const float*)d_in[2];
    const float* b_out = (const float*)d_in[3];
    float* out = (float*)d_out;

    char* ws = (char*)d_ws;
    const size_t pf_bytes = (size_t)K_ * B_ * sizeof(float);   // 33.55 MB
    float*  pfT   = (float*)(ws);                              // [K, B]
    float*  pf    = (float*)(ws + pf_bytes);                   // [B, K]
    float2* ocs   = (float2*)(ws + 2 * pf_bytes);              // [NPAIR_] (180 KB)
    float4* smeta = (float4*)(ws + 2 * pf_bytes + 256 * 1024); // [NPAIR_] (360 KB)
    int* chunkstart = (int*)(ws + 2 * pf_bytes + 768 * 1024);  // [NCH_+1]

    (void)hipFuncSetAttribute((const void*)pf_kernel,
                              hipFuncAttributeMaxDynamicSharedMemorySize,
                              SMEM_BYTES_);

    prep_kernel<<<(B_ + 255) / 256, 256, 0, stream>>>(ids, ocs);
    bucket_kernel<<<1, 512, 0, stream>>>(ids, ocs, smeta, chunkstart);
    pf_kernel<<<NBLK_, PFTH_, SMEM_BYTES_, stream>>>((const float4*)W, smeta, chunkstart, pfT);
    transpose_kb<<<dim3(K_ / 64, B_ / 64), 256, 0, stream>>>(pfT, pf);
    topk_logits_kernel<<<B_, 256, 0, stream>>>(pf, w_out, b_out, out);
}